// Round 4
// baseline (352.997 us; speedup 1.0000x reference)
//
#include <hip/hip_runtime.h>
#include <hip/hip_bf16.h>

typedef __bf16 bf16;
typedef __bf16 bf16x8 __attribute__((ext_vector_type(8)));
typedef __bf16 bf16x4v __attribute__((ext_vector_type(4)));
typedef float f32x4 __attribute__((ext_vector_type(4)));

#define D_MODEL 512
#define T_SEQ   4096
#define NH      8
#define DH      64
#define M_ROWS  8192   // B*T
#define QK_SCALE 0.18033688011112042f   // 0.125 * log2(e), folded into Q

// ---------------- kernel 0: dtype detector ----------------------------------
__global__ __launch_bounds__(64) void detect_dtype(const unsigned short* __restrict__ xr,
                                                   int* __restrict__ flag)
{
  int lane = threadIdx.x;
  int cnt = 0;
  for (int i = lane; i < 4096; i += 64) {
    unsigned short u = xr[i];
    int e = (u >> 7) & 0xFF;
    bool insane = (e >= 133) || (e > 0 && e <= 96) || (e == 0 && (u & 0x7F) != 0);
    cnt += insane ? 1 : 0;
  }
#pragma unroll
  for (int off = 32; off >= 1; off >>= 1) cnt += __shfl_xor(cnt, off);
  if (lane == 0) *flag = (cnt > 400) ? 1 : 0;   // 1 = inputs are fp32
}

// ---------------- kernel 0b: convert x to bf16 -------------------------------
__global__ __launch_bounds__(256) void convert_x(const void* __restrict__ xr,
                                                 const int* __restrict__ flag,
                                                 bf16* __restrict__ xb, int n)
{
  int i = (blockIdx.x * blockDim.x + threadIdx.x) * 4;
  if (i >= n) return;
  if (*flag) {
    float4 v = *(const float4*)((const float*)xr + i);
    __align__(8) bf16 o[4] = {(bf16)v.x, (bf16)v.y, (bf16)v.z, (bf16)v.w};
    *(uint2*)(xb + i) = *(uint2*)o;
  } else {
    *(uint2*)(xb + i) = *(const uint2*)((const bf16*)xr + i);
  }
}

// ---------------- kernel 0c: biases -> fp32 ----------------------------------
__global__ __launch_bounds__(256) void convert_bias(
    const void* b0, const void* b1, const void* b2, const void* b3,
    const int* __restrict__ flag, float* __restrict__ bf)
{
  const void* ps[4] = {b0, b1, b2, b3};
  int fl = *flag;
  for (int t = threadIdx.x; t < 4 * D_MODEL; t += 256) {
    int w = t >> 9, o = t & 511;
    bf[t] = fl ? ((const float*)ps[w])[o] : (float)((const bf16*)ps[w])[o];
  }
}

// ---------------- kernel 1: per-output-channel weight quant-dequant ----------
__global__ __launch_bounds__(256) void qdq_weights(
    const void* __restrict__ Wq, const void* __restrict__ Wk,
    const void* __restrict__ Wv, const void* __restrict__ Wo,
    const int* __restrict__ flag, bf16* __restrict__ out)
{
  int wave = threadIdx.x >> 6, lane = threadIdx.x & 63;
  int gid = blockIdx.x * 4 + wave;
  int w = gid >> 9, row = gid & 511;
  const void* W = (w == 0) ? Wq : (w == 1) ? Wk : (w == 2) ? Wv : Wo;
  int fl = *flag;
  float v[8]; float amax = 0.f;
#pragma unroll
  for (int i = 0; i < 8; i++) {
    int idx = row * D_MODEL + lane + 64 * i;
    v[i] = fl ? ((const float*)W)[idx] : (float)((const bf16*)W)[idx];
    amax = fmaxf(amax, fabsf(v[i]));
  }
#pragma unroll
  for (int off = 32; off >= 1; off >>= 1) amax = fmaxf(amax, __shfl_xor(amax, off));
  float s = fmaxf(amax / 127.0f, 1e-8f);
  bf16* dst = out + (size_t)gid * D_MODEL;
#pragma unroll
  for (int i = 0; i < 8; i++) {
    float q = rintf(v[i] / s);
    q = fminf(fmaxf(q, -127.f), 127.f);
    dst[lane + 64*i] = (bf16)(q * s);
  }
}

// ---------------- kernel 2a: fused QKV GEMM ----------------------------------
// C = x @ [Wq;Wk;Wv]^T + bias. grid (64, 12), 128x128 tiles. Section by n0:
// 0..511 -> Qm (scaled by QK_SCALE), 512..1023 -> Km, 1024..1535 -> VT (transposed).
#define LDS_STRIDE 40
__global__ __launch_bounds__(256) void gemm_qkv(
    const bf16* __restrict__ A, const bf16* __restrict__ W,
    const float* __restrict__ bias,
    bf16* __restrict__ Qm, bf16* __restrict__ Km, bf16* __restrict__ VT)
{
  __shared__ __align__(16) bf16 As[128 * LDS_STRIDE];
  __shared__ __align__(16) bf16 Bs[128 * LDS_STRIDE];

  const int tid = threadIdx.x;
  const int wave = tid >> 6, lane = tid & 63;
  const int lr = lane & 15, quad = lane >> 4;
  const int wm = (wave >> 1) * 64, wn = (wave & 1) * 64;
  const int m0 = blockIdx.x * 128, n0 = blockIdx.y * 128;
  const int sec = blockIdx.y >> 2;   // 0=Q 1=K 2=V

  f32x4 acc[4][4];
#pragma unroll
  for (int i = 0; i < 4; i++)
#pragma unroll
    for (int j = 0; j < 4; j++) acc[i][j] = f32x4{0.f, 0.f, 0.f, 0.f};

  const int srow = tid >> 2;
  const int sseg = (tid & 3) * 8;

  for (int k0 = 0; k0 < D_MODEL; k0 += 32) {
#pragma unroll
    for (int i = 0; i < 2; i++) {
      int r = srow + i * 64;
      *(uint4*)&As[r * LDS_STRIDE + sseg] = *(const uint4*)(A + (size_t)(m0 + r) * D_MODEL + k0 + sseg);
      *(uint4*)&Bs[r * LDS_STRIDE + sseg] = *(const uint4*)(W + (size_t)(n0 + r) * D_MODEL + k0 + sseg);
    }
    __syncthreads();
    bf16x8 af[4], bfr[4];
#pragma unroll
    for (int mt = 0; mt < 4; mt++) af[mt]  = *(bf16x8*)&As[(wm + mt*16 + lr) * LDS_STRIDE + quad*8];
#pragma unroll
    for (int nt = 0; nt < 4; nt++) bfr[nt] = *(bf16x8*)&Bs[(wn + nt*16 + lr) * LDS_STRIDE + quad*8];
#pragma unroll
    for (int mt = 0; mt < 4; mt++)
#pragma unroll
      for (int nt = 0; nt < 4; nt++)
        acc[mt][nt] = __builtin_amdgcn_mfma_f32_16x16x32_bf16(af[mt], bfr[nt], acc[mt][nt], 0, 0, 0);
    __syncthreads();
  }

  const float scale = (sec == 0) ? QK_SCALE : 1.0f;
#pragma unroll
  for (int mt = 0; mt < 4; mt++) {
    int grow = m0 + wm + mt * 16 + quad * 4;
#pragma unroll
    for (int nt = 0; nt < 4; nt++) {
      int gcol = n0 + wn + nt * 16 + lr;
      float b = bias[gcol];
      if (sec == 2) {               // VT[ch][token], packed x4
        bf16x4v pk;
#pragma unroll
        for (int r = 0; r < 4; r++) pk[r] = (bf16)(acc[mt][nt][r] + b);
        *(bf16x4v*)(VT + (size_t)(gcol - 1024) * M_ROWS + grow) = pk;
      } else {
        bf16* dst = (sec == 0) ? Qm : Km;
        int c = gcol & 511;
#pragma unroll
        for (int r = 0; r < 4; r++)
          dst[(size_t)(grow + r) * D_MODEL + c] = (bf16)((acc[mt][nt][r] + b) * scale);
      }
    }
  }
}

// ---------------- kernel 2b: O-proj GEMM, 64x128 tile, fp32 out + absmax -----
__global__ __launch_bounds__(256) void gemm_o(
    const bf16* __restrict__ A, const bf16* __restrict__ W,
    const float* __restrict__ bias,
    float* __restrict__ Cf, unsigned int* __restrict__ amaxp)
{
  __shared__ __align__(16) bf16 As[64 * LDS_STRIDE];
  __shared__ __align__(16) bf16 Bs[128 * LDS_STRIDE];
  __shared__ float wred[4];

  const int tid = threadIdx.x;
  const int wave = tid >> 6, lane = tid & 63;
  const int lr = lane & 15, quad = lane >> 4;
  const int wm = (wave >> 1) * 32, wn = (wave & 1) * 64;
  const int m0 = blockIdx.x * 64, n0 = blockIdx.y * 128;

  f32x4 acc[2][4];
#pragma unroll
  for (int i = 0; i < 2; i++)
#pragma unroll
    for (int j = 0; j < 4; j++) acc[i][j] = f32x4{0.f, 0.f, 0.f, 0.f};

  const int srow = tid >> 2;
  const int sseg = (tid & 3) * 8;

  for (int k0 = 0; k0 < D_MODEL; k0 += 32) {
    *(uint4*)&As[srow * LDS_STRIDE + sseg] = *(const uint4*)(A + (size_t)(m0 + srow) * D_MODEL + k0 + sseg);
#pragma unroll
    for (int i = 0; i < 2; i++) {
      int r = srow + i * 64;
      *(uint4*)&Bs[r * LDS_STRIDE + sseg] = *(const uint4*)(W + (size_t)(n0 + r) * D_MODEL + k0 + sseg);
    }
    __syncthreads();
    bf16x8 af[2], bfr[4];
#pragma unroll
    for (int mt = 0; mt < 2; mt++) af[mt]  = *(bf16x8*)&As[(wm + mt*16 + lr) * LDS_STRIDE + quad*8];
#pragma unroll
    for (int nt = 0; nt < 4; nt++) bfr[nt] = *(bf16x8*)&Bs[(wn + nt*16 + lr) * LDS_STRIDE + quad*8];
#pragma unroll
    for (int mt = 0; mt < 2; mt++)
#pragma unroll
      for (int nt = 0; nt < 4; nt++)
        acc[mt][nt] = __builtin_amdgcn_mfma_f32_16x16x32_bf16(af[mt], bfr[nt], acc[mt][nt], 0, 0, 0);
    __syncthreads();
  }

  float lmax = 0.f;
#pragma unroll
  for (int mt = 0; mt < 2; mt++) {
    int grow = m0 + wm + mt * 16 + quad * 4;
#pragma unroll
    for (int nt = 0; nt < 4; nt++) {
      int gcol = n0 + wn + nt * 16 + lr;
      float b = bias[gcol];
#pragma unroll
      for (int r = 0; r < 4; r++) {
        float v = acc[mt][nt][r] + b;
        Cf[(size_t)(grow + r) * D_MODEL + gcol] = v;
        lmax = fmaxf(lmax, fabsf(v));
      }
    }
  }
#pragma unroll
  for (int off = 32; off >= 1; off >>= 1) lmax = fmaxf(lmax, __shfl_xor(lmax, off));
  if (lane == 0) wred[wave] = lmax;
  __syncthreads();
  if (tid == 0) {
    float m = fmaxf(fmaxf(wred[0], wred[1]), fmaxf(wred[2], wred[3]));
    atomicMax(amaxp, __float_as_uint(m));
  }
}

// ---------------- kernel 3: flash attention, S^T, 128-q blocks ---------------
// grid (T/128, B*H), 4 waves; wave = 32 q (2 sub-tiles of 16), 64-key chunks.
// Q pre-scaled by 0.125*log2e -> exp2f softmax.
#define KV_STRIDE 72
__global__ __launch_bounds__(256, 4) void attn(
    const bf16* __restrict__ Q, const bf16* __restrict__ K, const bf16* __restrict__ VT,
    const int* __restrict__ mask, bf16* __restrict__ ctx)
{
  __shared__ __align__(16) bf16 Ks [64 * KV_STRIDE];
  __shared__ __align__(16) bf16 VTs[64 * KV_STRIDE];
  __shared__ __align__(16) bf16 Pb [4][32 * KV_STRIDE];
  __shared__ __align__(16) float Msk[64];

  const int tid = threadIdx.x, wave = tid >> 6, lane = tid & 63;
  const int lr = lane & 15, quad = lane >> 4;
  const int bh = blockIdx.y; const int b = bh >> 3, h = bh & 7;
  const int qbase = blockIdx.x * 128 + wave * 32;

  bf16x8 qf[2][2];
#pragma unroll
  for (int s = 0; s < 2; s++) {
    const size_t rowQ = (size_t)(b * T_SEQ + qbase + s*16 + lr) * D_MODEL + h * DH;
    qf[s][0] = *(const bf16x8*)(Q + rowQ + quad * 8);
    qf[s][1] = *(const bf16x8*)(Q + rowQ + 32 + quad * 8);
  }

  f32x4 O[2][4];
#pragma unroll
  for (int s = 0; s < 2; s++)
#pragma unroll
    for (int i = 0; i < 4; i++) O[s][i] = f32x4{0.f, 0.f, 0.f, 0.f};
  float mrow[2] = {-1e30f, -1e30f}, lrow[2] = {0.f, 0.f};

  const int srow = tid >> 2;
  const int sseg = (tid & 3) * 16;
  const int* maskb = mask + b * T_SEQ;

  for (int kb = 0; kb < T_SEQ; kb += 64) {
    {
      const bf16* gK = K  + (size_t)(b * T_SEQ + kb + srow) * D_MODEL + h * DH + sseg;
      const bf16* gV = VT + (size_t)(h * DH + srow) * M_ROWS + b * T_SEQ + kb + sseg;
      *(uint4*)&Ks [srow * KV_STRIDE + sseg]     = *(const uint4*)gK;
      *(uint4*)&Ks [srow * KV_STRIDE + sseg + 8] = *(const uint4*)(gK + 8);
      *(uint4*)&VTs[srow * KV_STRIDE + sseg]     = *(const uint4*)gV;
      *(uint4*)&VTs[srow * KV_STRIDE + sseg + 8] = *(const uint4*)(gV + 8);
      if (tid < 64) Msk[tid] = maskb[kb + tid] ? 0.f : -1e30f;
    }
    __syncthreads();

    // S^T[key=16mt+4quad+r][q] for both q sub-tiles; kf shared
    f32x4 S[2][4];
#pragma unroll
    for (int mt = 0; mt < 4; mt++) {
      bf16x8 kf0 = *(bf16x8*)&Ks[(mt*16 + lr) * KV_STRIDE + quad*8];
      bf16x8 kf1 = *(bf16x8*)&Ks[(mt*16 + lr) * KV_STRIDE + 32 + quad*8];
      f32x4 mk = *(f32x4*)&Msk[mt*16 + quad*4];
#pragma unroll
      for (int s = 0; s < 2; s++) {
        f32x4 z = f32x4{0.f, 0.f, 0.f, 0.f};
        z = __builtin_amdgcn_mfma_f32_16x16x32_bf16(kf0, qf[s][0], z, 0, 0, 0);
        z = __builtin_amdgcn_mfma_f32_16x16x32_bf16(kf1, qf[s][1], z, 0, 0, 0);
#pragma unroll
        for (int r = 0; r < 4; r++) S[s][mt][r] = z[r] + mk[r];
      }
    }

    float alpha[2];
#pragma unroll
    for (int s = 0; s < 2; s++) {
      float cm = -1e30f;
#pragma unroll
      for (int mt = 0; mt < 4; mt++)
#pragma unroll
        for (int r = 0; r < 4; r++) cm = fmaxf(cm, S[s][mt][r]);
      cm = fmaxf(cm, __shfl_xor(cm, 16));
      cm = fmaxf(cm, __shfl_xor(cm, 32));
      float mn = fmaxf(mrow[s], cm);
      alpha[s] = exp2f(mrow[s] - mn);
      mrow[s] = mn;
      float ls = 0.f;
#pragma unroll
      for (int mt = 0; mt < 4; mt++) {
        bf16x4v pk;
#pragma unroll
        for (int r = 0; r < 4; r++) {
          float p = exp2f(S[s][mt][r] - mn);
          ls += p;
          pk[r] = (bf16)p;
        }
        *(bf16x4v*)&Pb[wave][(s*16 + lr) * KV_STRIDE + mt*16 + quad*4] = pk;
      }
      ls += __shfl_xor(ls, 16);
      ls += __shfl_xor(ls, 32);
      lrow[s] = lrow[s] * alpha[s] + ls;
    }

    float aO[2][4];
#pragma unroll
    for (int s = 0; s < 2; s++)
#pragma unroll
      for (int r = 0; r < 4; r++) aO[s][r] = __shfl(alpha[s], quad*4 + r);

    bf16x8 pf[2][2];
#pragma unroll
    for (int s = 0; s < 2; s++) {
      pf[s][0] = *(bf16x8*)&Pb[wave][(s*16 + lr) * KV_STRIDE + quad*8];
      pf[s][1] = *(bf16x8*)&Pb[wave][(s*16 + lr) * KV_STRIDE + 32 + quad*8];
    }
#pragma unroll
    for (int nt = 0; nt < 4; nt++) {
      bf16x8 vf0 = *(bf16x8*)&VTs[(nt*16 + lr) * KV_STRIDE + quad*8];
      bf16x8 vf1 = *(bf16x8*)&VTs[(nt*16 + lr) * KV_STRIDE + 32 + quad*8];
#pragma unroll
      for (int s = 0; s < 2; s++) {
        f32x4 o = O[s][nt];
#pragma unroll
        for (int r = 0; r < 4; r++) o[r] *= aO[s][r];
        o = __builtin_amdgcn_mfma_f32_16x16x32_bf16(pf[s][0], vf0, o, 0, 0, 0);
        o = __builtin_amdgcn_mfma_f32_16x16x32_bf16(pf[s][1], vf1, o, 0, 0, 0);
        O[s][nt] = o;
      }
    }
    __syncthreads();
  }

#pragma unroll
  for (int s = 0; s < 2; s++) {
    float linv = 1.0f / lrow[s];
    float lO[4];
#pragma unroll
    for (int r = 0; r < 4; r++) lO[r] = __shfl(linv, quad*4 + r);
#pragma unroll
    for (int nt = 0; nt < 4; nt++)
#pragma unroll
      for (int r = 0; r < 4; r++) {
        size_t row = (size_t)(b * T_SEQ + qbase + s*16 + quad*4 + r);
        ctx[row * D_MODEL + h * DH + nt*16 + lr] = (bf16)(O[s][nt][r] * lO[r]);
      }
  }
}

// ---------------- kernel 4: per-tensor activation quant-dequant --------------
__global__ __launch_bounds__(256) void act_qdq(
    const float* __restrict__ pre, const unsigned int* __restrict__ amaxp,
    const int* __restrict__ flag, void* __restrict__ outv, int n)
{
  int i = (blockIdx.x * blockDim.x + threadIdx.x) * 4;
  if (i >= n) return;
  float s = fmaxf(__uint_as_float(*amaxp) / 127.0f, 1e-8f);
  float4 v = *(const float4*)(pre + i);
  float o[4] = {v.x, v.y, v.z, v.w};
#pragma unroll
  for (int r = 0; r < 4; r++) {
    float q = rintf(o[r] / s);
    q = fminf(fmaxf(q, -127.f), 127.f);
    o[r] = q * s;
  }
  if (*flag) {
    *(float4*)((float*)outv + i) = make_float4(o[0], o[1], o[2], o[3]);
  } else {
    __align__(8) bf16 ob[4] = {(bf16)o[0], (bf16)o[1], (bf16)o[2], (bf16)o[3]};
    *(uint2*)((bf16*)outv + i) = *(uint2*)ob;
  }
}

// ---------------- launch -----------------------------------------------------
extern "C" void kernel_launch(void* const* d_in, const int* in_sizes, int n_in,
                              void* d_out, int out_size, void* d_ws, size_t ws_size,
                              hipStream_t stream) {
  const void* x    = d_in[0];
  const int*  mask = (const int*)d_in[1];
  const void* Wq = d_in[2]; const void* bq = d_in[3];
  const void* Wk = d_in[4]; const void* bk = d_in[5];
  const void* Wv = d_in[6]; const void* bv = d_in[7];
  const void* Wo = d_in[8]; const void* bo = d_in[9];

  char* ws = (char*)d_ws;
  int*  flag  = (int*)(ws + 0);
  unsigned int* amax = (unsigned int*)(ws + 64);
  float* biasf = (float*)(ws + 1024);
  bf16* Wt  = (bf16*)(ws + 16384);                    // 2 MB (rows: Q,K,V,O)
  bf16* xb  = (bf16*)(ws + 4194304);                  // 8 MB
  bf16* Qm  = (bf16*)(ws + 12582912);                 // 8 MB (pre-scaled)
  bf16* Km  = (bf16*)(ws + 20971520);                 // 8 MB
  bf16* VT  = (bf16*)(ws + 29360128);                 // 8 MB: VT[ch][token]
  bf16* Cm  = (bf16*)(ws + 4194304);                  // overlays xb
  float* pre = (float*)(ws + 12582912);               // overlays Qm+Km

  hipMemsetAsync(amax, 0, 4, stream);
  detect_dtype<<<1, 64, 0, stream>>>((const unsigned short*)x, flag);
  convert_x<<<4096, 256, 0, stream>>>(x, flag, xb, M_ROWS * D_MODEL);
  convert_bias<<<1, 256, 0, stream>>>(bq, bk, bv, bo, flag, biasf);
  qdq_weights<<<512, 256, 0, stream>>>(Wq, Wk, Wv, Wo, flag, Wt);
  gemm_qkv<<<dim3(64, 12), 256, 0, stream>>>(xb, Wt, biasf, Qm, Km, VT);
  attn<<<dim3(32, 16), 256, 0, stream>>>(Qm, Km, VT, mask, Cm);
  gemm_o<<<dim3(128, 4), 256, 0, stream>>>(Cm, Wt + 3*262144, biasf + 1536, pre, amax);
  act_qdq<<<4096, 256, 0, stream>>>(pre, amax, flag, d_out, M_ROWS * D_MODEL);
}